// Round 9
// baseline (779.896 us; speedup 1.0000x reference)
//
#include <hip/hip_runtime.h>
#include <math.h>

#define BSZ   32768
#define FDIM  256
#define HDIM  128
#define OUTD  64
#define SQRT_HALF 0.70710678118654752f
#define BN_EPS 1e-5f
#define SM_EPS 1e-5f
#define INV_B (1.0f / 32768.0f)

typedef __attribute__((ext_vector_type(8))) short bf16x8;
typedef __attribute__((ext_vector_type(4))) float f32x4;

__device__ __forceinline__ float b2f(unsigned short u) {
    return __uint_as_float(((unsigned int)u) << 16);
}
__device__ __forceinline__ unsigned short f2b(float f) {
    unsigned int u = __float_as_uint(f);
    u += 0x7fff + ((u >> 16) & 1);   // RNE
    return (unsigned short)(u >> 16);
}

// async global->LDS, 16B per lane; LDS dest = wave-uniform base + lane*16
__device__ __forceinline__ void async16(const void* g, void* l) {
    __builtin_amdgcn_global_load_lds(
        (const __attribute__((address_space(1))) void*)(uintptr_t)g,
        (__attribute__((address_space(3))) void*)(unsigned int)(uintptr_t)l,
        16, 0, 0);
}

__device__ inline float waveMaxAll(float v) {
#pragma unroll
    for (int m = 32; m > 0; m >>= 1) v = fmaxf(v, __shfl_xor(v, m, 64));
    return v;
}
__device__ inline float waveSumAll(float v) {
#pragma unroll
    for (int m = 32; m > 0; m >>= 1) v += __shfl_xor(v, m, 64);
    return v;
}

// 64-row tiles: 1024 blocks = 512 row-tiles x 2 col-tiles.
// XCD-pair swizzle: blocks b and b+8 (same XCD) take the two column tiles
// of the same 64-row stripe -> Pprev reads dedupe in that XCD's L2.
__device__ __forceinline__ void swizzle64(int b, int& row0, int& col0, int& bx) {
    const int by = ((b >> 4) << 3) | (b & 7);   // 0..511
    bx = (b >> 3) & 1;
    row0 = by * 64;
    col0 = bx * 128;
}

// ---------------- weight prep: fp32 (K x 256) -> bf16 transposed (256 x K) ----------------
__global__ __launch_bounds__(256) void prep_w(
    const float* __restrict__ W1, const float* __restrict__ W2,
    const float* __restrict__ W3, const float* __restrict__ W4,
    const float* __restrict__ Wc,
    unsigned short* __restrict__ W1t, unsigned short* __restrict__ W2t,
    unsigned short* __restrict__ W3t, unsigned short* __restrict__ W4t,
    unsigned short* __restrict__ Wct)
{
    const int m = blockIdx.x, kz = blockIdx.y, n = threadIdx.x;
    const float* src; unsigned short* dst; int K;
    if (m == 0)      { src = W1;                        dst = W1t;               K = 256; }
    else if (m == 1) { src = W2;                        dst = W2t;               K = 128; }
    else if (m < 7)  { int i = m - 2;  src = W3 + (size_t)i * 128 * 256; dst = W3t + (size_t)i * 32768; K = 128; }
    else if (m < 12) { int i = m - 7;  src = W4 + (size_t)i * 128 * 256; dst = W4t + (size_t)i * 32768; K = 128; }
    else             { int i = m - 12; src = Wc + (size_t)i * 64 * 256;  dst = Wct + (size_t)i * 16384; K = 64; }
    const int k0 = kz * 32;
    if (k0 >= K) return;
    for (int k = k0; k < k0 + 32; ++k)
        dst[(size_t)n * K + k] = f2b(src[(size_t)k * 256 + n]);
}

// ---------------- column stats for x (B x 256), float4 loads ----------------
__global__ __launch_bounds__(256) void colstats(const float* __restrict__ X,
                                                float* __restrict__ stats) {
    __shared__ float red[4][512];
    const int sub = threadIdx.x >> 6;          // 0..3
    const int c4  = (threadIdx.x & 63) << 2;   // col base
    float s[4] = {0.f, 0.f, 0.f, 0.f}, q[4] = {0.f, 0.f, 0.f, 0.f};
#pragma unroll 8
    for (int i = 0; i < 32; ++i) {
        const int row = blockIdx.x * 128 + i * 4 + sub;
        float4 v = *(const float4*)(X + (size_t)row * 256 + c4);
        s[0] += v.x; q[0] += v.x * v.x;
        s[1] += v.y; q[1] += v.y * v.y;
        s[2] += v.z; q[2] += v.z * v.z;
        s[3] += v.w; q[3] += v.w * v.w;
    }
#pragma unroll
    for (int e = 0; e < 4; ++e) {
        red[sub][c4 + e] = s[e];
        red[sub][256 + c4 + e] = q[e];
    }
    __syncthreads();
    const int t = threadIdx.x;
    float sS = red[0][t] + red[1][t] + red[2][t] + red[3][t];
    float sQ = red[0][256 + t] + red[1][256 + t] + red[2][256 + t] + red[3][256 + t];
    atomicAdd(&stats[t], sS);
    atomicAdd(&stats[256 + t], sQ);
}

// ---------------- normalize x -> xb(bf16), out = 5*relu(x_bn[:, :64]) ----------------
__global__ __launch_bounds__(256) void norm_x(const float* __restrict__ x,
                                              const float* __restrict__ stats,
                                              const float* __restrict__ g,
                                              const float* __restrict__ b,
                                              unsigned short* __restrict__ xb,
                                              float* __restrict__ out) {
    const int i4 = blockIdx.x * 256 + threadIdx.x;   // B*64 total
    const int row = i4 >> 6, c4 = (i4 & 63) << 2;
    float4 xv = *(const float4*)(x + (size_t)row * 256 + c4);
    float4 sv = *(const float4*)&stats[c4];
    float4 qv = *(const float4*)&stats[256 + c4];
    float4 gv = *(const float4*)&g[c4];
    float4 bv = *(const float4*)&b[c4];
    const float* xp = (const float*)&xv; const float* sp = (const float*)&sv;
    const float* qp = (const float*)&qv; const float* gp = (const float*)&gv;
    const float* bp = (const float*)&bv;
    float n[4];
    ushort4 ob;
    unsigned short* obp = (unsigned short*)&ob;
#pragma unroll
    for (int e = 0; e < 4; ++e) {
        float mean = sp[e] * INV_B;
        float var  = qp[e] * INV_B - mean * mean;
        float sc   = gp[e] * rsqrtf(var + BN_EPS);
        float sh   = bp[e] - mean * sc;
        n[e] = xp[e] * sc + sh;
        obp[e] = f2b(n[e]);
    }
    *(ushort4*)(xb + (size_t)row * 256 + c4) = ob;
    if (c4 < OUTD) {
        float4 ov = make_float4(5.0f * fmaxf(n[0], 0.f), 5.0f * fmaxf(n[1], 0.f),
                                5.0f * fmaxf(n[2], 0.f), 5.0f * fmaxf(n[3], 0.f));
        *(float4*)(out + (size_t)row * OUTD + c4) = ov;
    }
}

// ---------------- shared epilogue: P write + column stats (64-row tile) ----------------
__device__ __forceinline__ void gemm_epilogue64(
    f32x4 (&acc)[2][4], int row0, int col0, int waveM, int waveN,
    int lane, int tid,
    float (*redS)[128], float (*redQ)[128],
    unsigned short* __restrict__ Pout, float* __restrict__ stats)
{
    const int fm = lane & 15;
    const int orow = row0 + waveM * 32 + (lane >> 4) * 4;
    const int ocol = col0 + waveN * 64 + fm;
#pragma unroll
    for (int i = 0; i < 2; ++i)
#pragma unroll
        for (int j = 0; j < 4; ++j)
#pragma unroll
            for (int r = 0; r < 4; ++r)
                Pout[(size_t)(orow + i * 16 + r) * 256 + (ocol + j * 16)] = f2b(acc[i][j][r]);

#pragma unroll
    for (int j = 0; j < 4; ++j) {
        float s = 0.f, q = 0.f;
#pragma unroll
        for (int i = 0; i < 2; ++i)
#pragma unroll
            for (int r = 0; r < 4; ++r) {
                float v = acc[i][j][r];
                s += v; q += v * v;
            }
        s += __shfl_xor(s, 16, 64); s += __shfl_xor(s, 32, 64);
        q += __shfl_xor(q, 16, 64); q += __shfl_xor(q, 32, 64);
        if (lane < 16) {
            redS[waveM][waveN * 64 + j * 16 + lane] = s;
            redQ[waveM][waveN * 64 + j * 16 + lane] = q;
        }
    }
    __syncthreads();
    if (tid < 128) {
        atomicAdd(&stats[col0 + tid], redS[0][tid] + redS[1][tid]);
    } else {
        const int t = tid - 128;
        atomicAdd(&stats[256 + col0 + t], redQ[0][t] + redQ[1][t]);
    }
}

// ---------------- plain bf16 MFMA GEMM (stage 1), 64x128 tile ----------------
__global__ __launch_bounds__(256) void gemm_bf16(
    const unsigned short* __restrict__ A,
    const unsigned short* __restrict__ Wt, int K,
    unsigned short* __restrict__ P,
    float* __restrict__ stats)
{
    __shared__ short As[64 * 32];    // 4 KB
    __shared__ short Bs[128 * 32];   // 8 KB
    __shared__ float redS[2][128];
    __shared__ float redQ[2][128];

    const int tid  = threadIdx.x;
    const int wave = tid >> 6;
    const int lane = tid & 63;
    const int waveM = wave >> 1, waveN = wave & 1;
    int row0, col0, bx;
    swizzle64(blockIdx.x, row0, col0, bx);

    const int sr = lane >> 2;
    const int sc = (lane & 3) * 8;
    const int fm = lane & 15;
    const int fq = (lane >> 4) * 8;

    f32x4 acc[2][4];
#pragma unroll
    for (int i = 0; i < 2; ++i)
#pragma unroll
        for (int j = 0; j < 4; ++j)
            acc[i][j] = (f32x4){0.f, 0.f, 0.f, 0.f};

    for (int k0 = 0; k0 < K; k0 += 32) {
        // A: 64 rows, one async16 per thread
        async16(A + (size_t)(row0 + wave * 16 + sr) * K + k0 + sc,
                (void*)(As + wave * 512 + lane * 8));
        // B: 128 rows, two per thread
#pragma unroll
        for (int t = 0; t < 2; ++t) {
            const int rr = (wave * 2 + t) * 16 + sr;
            async16(Wt + (size_t)(col0 + rr) * K + k0 + sc,
                    (void*)(Bs + (wave * 2 + t) * 512 + lane * 8));
        }
        __syncthreads();

        bf16x8 af[2], bfr[4];
#pragma unroll
        for (int i = 0; i < 2; ++i)
            af[i] = *(const bf16x8*)(As + (waveM * 32 + i * 16 + fm) * 32 + fq);
#pragma unroll
        for (int j = 0; j < 4; ++j)
            bfr[j] = *(const bf16x8*)(Bs + (waveN * 64 + j * 16 + fm) * 32 + fq);
#pragma unroll
        for (int i = 0; i < 2; ++i)
#pragma unroll
            for (int j = 0; j < 4; ++j)
                acc[i][j] = __builtin_amdgcn_mfma_f32_16x16x32_bf16(af[i], bfr[j], acc[i][j], 0, 0, 0);
        __syncthreads();
    }

    gemm_epilogue64(acc, row0, col0, waveM, waveN, lane, tid, redS, redQ, P, stats);
}

// ---------------- fused BN+GLU(+res) prologue GEMM, 64x128 tile ----------------
template <bool RES, bool WRITE_H>
__global__ __launch_bounds__(256) void gemm_glu(
    const unsigned short* __restrict__ Pprev,
    const float* __restrict__ pstats,
    const float* __restrict__ pg,
    const float* __restrict__ pb,
    const unsigned short* __restrict__ res,   // pre-offset, lda 128
    int colOff,
    const unsigned short* __restrict__ Wt, int K,
    unsigned short* __restrict__ Pout,
    float* __restrict__ stats,
    unsigned short* __restrict__ hOut)
{
    __shared__ short As[64 * 32];
    __shared__ short Bs[128 * 32];
    __shared__ float redS[2][128];
    __shared__ float redQ[2][128];
    __shared__ float tScA[128], tShA[128], tScG[128], tShG[128];

    const int tid  = threadIdx.x;
    const int wave = tid >> 6;
    const int lane = tid & 63;
    const int waveM = wave >> 1, waveN = wave & 1;
    int row0, col0, bx;
    swizzle64(blockIdx.x, row0, col0, bx);

    // per-column BN affine tables
    if (tid < K) {
        const int ch = colOff + tid;
        float ma = pstats[ch] * INV_B;
        float va = pstats[256 + ch] * INV_B - ma * ma;
        float sA = pg[ch] * rsqrtf(va + BN_EPS);
        tScA[tid] = sA; tShA[tid] = pb[ch] - ma * sA;
        const int cg = ch + 128;
        float mg = pstats[cg] * INV_B;
        float vg = pstats[256 + cg] * INV_B - mg * mg;
        float sG = pg[cg] * rsqrtf(vg + BN_EPS);
        tScG[tid] = sG; tShG[tid] = pb[cg] - mg * sG;
    }
    __syncthreads();

    const int sr = lane >> 2;
    const int sc = (lane & 3) * 8;
    const int ar = tid >> 2;          // A row 0..63
    const int ac = (tid & 3) * 8;     // A k base
    const int fm = lane & 15;
    const int fq = (lane >> 4) * 8;

    f32x4 acc[2][4];
#pragma unroll
    for (int i = 0; i < 2; ++i)
#pragma unroll
        for (int j = 0; j < 4; ++j)
            acc[i][j] = (f32x4){0.f, 0.f, 0.f, 0.f};

    for (int k0 = 0; k0 < K; k0 += 32) {
        // B staging first (async DMAs in flight under the GLU compute)
#pragma unroll
        for (int t = 0; t < 2; ++t) {
            const int rr = (wave * 2 + t) * 16 + sr;
            async16(Wt + (size_t)(col0 + rr) * K + k0 + sc,
                    (void*)(Bs + (wave * 2 + t) * 512 + lane * 8));
        }

        // A prologue: one bf16x8 per thread
        {
            const int kk = k0 + ac;
            const size_t grow = (size_t)(row0 + ar);

            bf16x8 lo = *(const bf16x8*)(Pprev + grow * 256 + colOff + kk);
            bf16x8 hi = *(const bf16x8*)(Pprev + grow * 256 + colOff + kk + 128);
            bf16x8 rv;
            if (RES) rv = *(const bf16x8*)(res + grow * 128 + kk);

            float4 a0 = *(const float4*)&tScA[kk], a1 = *(const float4*)&tScA[kk + 4];
            float4 h0 = *(const float4*)&tShA[kk], h1 = *(const float4*)&tShA[kk + 4];
            float4 g0 = *(const float4*)&tScG[kk], g1 = *(const float4*)&tScG[kk + 4];
            float4 s0 = *(const float4*)&tShG[kk], s1 = *(const float4*)&tShG[kk + 4];
            float scA[8] = {a0.x, a0.y, a0.z, a0.w, a1.x, a1.y, a1.z, a1.w};
            float shA[8] = {h0.x, h0.y, h0.z, h0.w, h1.x, h1.y, h1.z, h1.w};
            float scG[8] = {g0.x, g0.y, g0.z, g0.w, g1.x, g1.y, g1.z, g1.w};
            float shG[8] = {s0.x, s0.y, s0.z, s0.w, s1.x, s1.y, s1.z, s1.w};

            bf16x8 o8;
#pragma unroll
            for (int e = 0; e < 8; ++e) {
                float na = b2f((unsigned short)lo[e]) * scA[e] + shA[e];
                float ng = b2f((unsigned short)hi[e]) * scG[e] + shG[e];
                float v = na * (1.0f / (1.0f + __expf(-ng)));
                if (RES) v = (v + b2f((unsigned short)rv[e])) * SQRT_HALF;
                o8[e] = (short)f2b(v);
            }
            *(bf16x8*)(As + ar * 32 + ac) = o8;
            if (WRITE_H && bx == 0)
                *(bf16x8*)(hOut + grow * 128 + kk) = o8;
        }
        __syncthreads();

        bf16x8 af[2], bfr[4];
#pragma unroll
        for (int i = 0; i < 2; ++i)
            af[i] = *(const bf16x8*)(As + (waveM * 32 + i * 16 + fm) * 32 + fq);
#pragma unroll
        for (int j = 0; j < 4; ++j)
            bfr[j] = *(const bf16x8*)(Bs + (waveN * 64 + j * 16 + fm) * 32 + fq);
#pragma unroll
        for (int i = 0; i < 2; ++i)
#pragma unroll
            for (int j = 0; j < 4; ++j)
                acc[i][j] = __builtin_amdgcn_mfma_f32_16x16x32_bf16(af[i], bfr[j], acc[i][j], 0, 0, 0);
        __syncthreads();
    }

    gemm_epilogue64(acc, row0, col0, waveM, waveN, lane, tid, redS, redQ, Pout, stats);
}

// ---------------- coef BN -> softmax -> mask/compl/entropy ----------------
// MODE 0: first (cmpl==1 implicit). MODE 1: middle. MODE 2: last (entropy only).
template <int MODE>
__global__ __launch_bounds__(256) void coef_mask(const unsigned short* __restrict__ Pc,
                                                 const float* __restrict__ stats,
                                                 const float* __restrict__ gc,
                                                 const float* __restrict__ bc,
                                                 const unsigned short* __restrict__ xb,
                                                 unsigned short* __restrict__ cmpl,
                                                 unsigned short* __restrict__ masked,
                                                 float* __restrict__ ent) {
    const int w    = threadIdx.x >> 6;
    const int lane = threadIdx.x & 63;
    const int row  = blockIdx.x * 4 + w;
    const int c    = lane << 2;
    __shared__ float went[4];

    float4 sv = *(const float4*)&stats[c];
    float4 qv = *(const float4*)&stats[256 + c];
    float4 gv = *(const float4*)&gc[c];
    float4 bv = *(const float4*)&bc[c];
    const float* svv = (const float*)&sv; const float* qvv = (const float*)&qv;
    const float* gvv = (const float*)&gv; const float* bvv = (const float*)&bv;

    float scl[4], shf[4];
#pragma unroll
    for (int e = 0; e < 4; ++e) {
        float mean = svv[e] * INV_B, var = qvv[e] * INV_B - mean * mean;
        scl[e] = gvv[e] * rsqrtf(var + BN_EPS);
        shf[e] = bvv[e] - mean * scl[e];
    }

    const size_t idx = (size_t)row * 256 + c;
    ushort4 pu = *(const ushort4*)(Pc + idx);
    const unsigned short* puv = (const unsigned short*)&pu;

    float cl[4] = {1.f, 1.f, 1.f, 1.f};
    if (MODE != 0) {
        ushort4 cu = *(const ushort4*)(cmpl + idx);
        const unsigned short* cuv = (const unsigned short*)&cu;
#pragma unroll
        for (int e = 0; e < 4; ++e) cl[e] = b2f(cuv[e]);
    }

    float l[4];
#pragma unroll
    for (int e = 0; e < 4; ++e) l[e] = (b2f(puv[e]) * scl[e] + shf[e]) * cl[e];

    float mx = waveMaxAll(fmaxf(fmaxf(l[0], l[1]), fmaxf(l[2], l[3])));
    float e0 = __expf(l[0] - mx), e1 = __expf(l[1] - mx),
          e2 = __expf(l[2] - mx), e3 = __expf(l[3] - mx);
    float inv = 1.0f / waveSumAll(e0 + e1 + e2 + e3);

    float m[4] = {e0 * inv, e1 * inv, e2 * inv, e3 * inv};

    float et = -m[0] * __logf(m[0] + SM_EPS) - m[1] * __logf(m[1] + SM_EPS)
             - m[2] * __logf(m[2] + SM_EPS) - m[3] * __logf(m[3] + SM_EPS);
    et = waveSumAll(et);
    if (lane == 0) went[w] = et;
    __syncthreads();
    if (threadIdx.x == 0) {
        float v = went[0] + went[1] + went[2] + went[3];
        atomicAdd(&ent[(blockIdx.x & 255) << 5], v * (INV_B * 0.2f));
    }

    if (MODE != 2) {
        ushort4 xu = *(const ushort4*)(xb + idx);
        const unsigned short* xuv = (const unsigned short*)&xu;
        ushort4 co, mo;
        unsigned short* cop = (unsigned short*)&co;
        unsigned short* mop = (unsigned short*)&mo;
#pragma unroll
        for (int e = 0; e < 4; ++e) {
            cop[e] = f2b(cl[e] * (1.5f - m[e]));
            mop[e] = f2b(m[e] * b2f(xuv[e]));
        }
        *(ushort4*)&cmpl[idx]   = co;
        *(ushort4*)&masked[idx] = mo;
    }
}

__global__ __launch_bounds__(64) void write_ent(const float* __restrict__ ent,
                                                float* __restrict__ dst) {
    const int lane = threadIdx.x;
    float v = 0.f;
#pragma unroll
    for (int i = 0; i < 4; ++i) v += ent[(lane + 64 * i) << 5];
    v = waveSumAll(v);
    if (lane == 0) dst[0] = v;
}

// ---------------- host orchestration ----------------
extern "C" void kernel_launch(void* const* d_in, const int* in_sizes, int n_in,
                              void* d_out, int out_size, void* d_ws, size_t ws_size,
                              hipStream_t stream) {
    const float* x     = (const float*)d_in[0];
    const float* enc_g = (const float*)d_in[1];
    const float* enc_b = (const float*)d_in[2];
    const float* W1 = (const float*)d_in[3];
    const float* g1 = (const float*)d_in[4];
    const float* b1 = (const float*)d_in[5];
    const float* W2 = (const float*)d_in[6];
    const float* g2 = (const float*)d_in[7];
    const float* b2 = (const float*)d_in[8];
    const float* W3 = (const float*)d_in[9];
    const float* g3 = (const float*)d_in[10];
    const float* b3 = (const float*)d_in[11];
    const float* W4 = (const float*)d_in[12];
    const float* g4 = (const float*)d_in[13];
    const float* b4 = (const float*)d_in[14];
    const float* Wc = (const float*)d_in[15];
    const float* gc = (const float*)d_in[16];
    const float* bc = (const float*)d_in[17];
    float* out = (float*)d_out;

    const size_t NBF = (size_t)BSZ * FDIM;   // 8388608
    const size_t NBH = (size_t)BSZ * HDIM;   // 4194304

    unsigned short* xb     = (unsigned short*)d_ws;
    unsigned short* masked = xb + NBF;       // doubles as P ping buffer Pb2
    unsigned short* Pb1    = masked + NBF;
    unsigned short* h1     = Pb1 + NBF;
    unsigned short* h2     = h1 + NBH;
    unsigned short* h3     = h2 + NBH;
    unsigned short* cmpl   = h3 + NBH;
    unsigned short* W1t    = cmpl + NBF;          // 65536
    unsigned short* W2t    = W1t + 65536;         // 32768
    unsigned short* W3t    = W2t + 32768;         // 5*32768
    unsigned short* W4t    = W3t + 163840;        // 5*32768
    unsigned short* Wct    = W4t + 163840;        // 5*16384
    float* stats = (float*)(Wct + 81920);         // 26 slots * 512
    float* ent   = stats + 26 * 512;              // 256 slots * 32 (128B spread)

    unsigned short* Pb2 = masked;

    hipMemsetAsync(stats, 0, (26 * 512 + 256 * 32) * sizeof(float), stream);

    prep_w<<<dim3(17, 8), 256, 0, stream>>>(W1, W2, W3, W4, Wc, W1t, W2t, W3t, W4t, Wct);
    colstats<<<256, 256, 0, stream>>>(x, stats);
    norm_x<<<8192, 256, 0, stream>>>(x, stats, enc_g, enc_b, xb, out);

    for (int ni = 0; ni < 5; ++ni) {
        float* s1 = stats + (size_t)(1 + ni * 5 + 0) * 512;
        float* s2 = stats + (size_t)(1 + ni * 5 + 1) * 512;
        float* s3 = stats + (size_t)(1 + ni * 5 + 2) * 512;
        float* s4 = stats + (size_t)(1 + ni * 5 + 3) * 512;
        float* s5 = stats + (size_t)(1 + ni * 5 + 4) * 512;

        const unsigned short* in1 = (ni == 0) ? xb : masked;

        gemm_bf16<<<1024, 256, 0, stream>>>(in1, W1t, 256, Pb1, s1);
        gemm_glu<false, true><<<1024, 256, 0, stream>>>(
            Pb1, s1, g1, b1, nullptr, 0, W2t, 128, Pb2, s2, h1);
        gemm_glu<true, true><<<1024, 256, 0, stream>>>(
            Pb2, s2, g2, b2, h1, 0, W3t + (size_t)ni * 32768, 128, Pb1, s3, h2);
        gemm_glu<true, true><<<1024, 256, 0, stream>>>(
            Pb1, s3, g3 + ni * 256, b3 + ni * 256, h2, 0,
            W4t + (size_t)ni * 32768, 128, Pb2, s4, h3);
        gemm_glu<true, false><<<1024, 256, 0, stream>>>(
            Pb2, s4, g4 + ni * 256, b4 + ni * 256, h3 + 64, 64,
            Wct + (size_t)ni * 16384, 64, Pb1, s5, nullptr);

        if (ni == 0)
            coef_mask<0><<<BSZ / 4, 256, 0, stream>>>(Pb1, s5, gc, bc, xb, cmpl, masked, ent);
        else if (ni < 4)
            coef_mask<1><<<BSZ / 4, 256, 0, stream>>>(Pb1, s5, gc + ni * 256, bc + ni * 256,
                                                      xb, cmpl, masked, ent);
        else
            coef_mask<2><<<BSZ / 4, 256, 0, stream>>>(Pb1, s5, gc + ni * 256, bc + ni * 256,
                                                      xb, cmpl, masked, ent);
    }

    write_ent<<<1, 64, 0, stream>>>(ent, out + (size_t)BSZ * OUTD);
}

// Round 10
// 613.446 us; speedup vs baseline: 1.2713x; 1.2713x over previous
//
#include <hip/hip_runtime.h>
#include <math.h>

#define BSZ   32768
#define FDIM  256
#define HDIM  128
#define OUTD  64
#define SQRT_HALF 0.70710678118654752f
#define BN_EPS 1e-5f
#define SM_EPS 1e-5f
#define INV_B (1.0f / 32768.0f)
#define NCPY  8          // stats copies (XCD-spread atomics)
#define SLOT  (NCPY * 512)

typedef __attribute__((ext_vector_type(8))) short bf16x8;
typedef __attribute__((ext_vector_type(4))) float f32x4;

__device__ __forceinline__ float b2f(unsigned short u) {
    return __uint_as_float(((unsigned int)u) << 16);
}
__device__ __forceinline__ unsigned short f2b(float f) {
    unsigned int u = __float_as_uint(f);
    u += 0x7fff + ((u >> 16) & 1);   // RNE
    return (unsigned short)(u >> 16);
}

// async global->LDS, 16B per lane; LDS dest = wave-uniform base + lane*16
__device__ __forceinline__ void async16(const void* g, void* l) {
    __builtin_amdgcn_global_load_lds(
        (const __attribute__((address_space(1))) void*)(uintptr_t)g,
        (__attribute__((address_space(3))) void*)(unsigned int)(uintptr_t)l,
        16, 0, 0);
}

__device__ inline float waveMaxAll(float v) {
#pragma unroll
    for (int m = 32; m > 0; m >>= 1) v = fmaxf(v, __shfl_xor(v, m, 64));
    return v;
}
__device__ inline float waveSumAll(float v) {
#pragma unroll
    for (int m = 32; m > 0; m >>= 1) v += __shfl_xor(v, m, 64);
    return v;
}

// ---------------- weight prep: fp32 (K x 256) -> bf16 transposed (256 x K) ----------------
__global__ __launch_bounds__(256) void prep_w(
    const float* __restrict__ W1, const float* __restrict__ W2,
    const float* __restrict__ W3, const float* __restrict__ W4,
    const float* __restrict__ Wc,
    unsigned short* __restrict__ W1t, unsigned short* __restrict__ W2t,
    unsigned short* __restrict__ W3t, unsigned short* __restrict__ W4t,
    unsigned short* __restrict__ Wct)
{
    const int m = blockIdx.x, kz = blockIdx.y, n = threadIdx.x;
    const float* src; unsigned short* dst; int K;
    if (m == 0)      { src = W1;                        dst = W1t;               K = 256; }
    else if (m == 1) { src = W2;                        dst = W2t;               K = 128; }
    else if (m < 7)  { int i = m - 2;  src = W3 + (size_t)i * 128 * 256; dst = W3t + (size_t)i * 32768; K = 128; }
    else if (m < 12) { int i = m - 7;  src = W4 + (size_t)i * 128 * 256; dst = W4t + (size_t)i * 32768; K = 128; }
    else             { int i = m - 12; src = Wc + (size_t)i * 64 * 256;  dst = Wct + (size_t)i * 16384; K = 64; }
    const int k0 = kz * 32;
    if (k0 >= K) return;
    for (int k = k0; k < k0 + 32; ++k)
        dst[(size_t)n * K + k] = f2b(src[(size_t)k * 256 + n]);
}

// ---------------- column stats for x (B x 256), float4 loads, 8-copy spread ----------------
__global__ __launch_bounds__(256) void colstats(const float* __restrict__ X,
                                                float* __restrict__ st0) {
    __shared__ float red[4][512];
    const int sub = threadIdx.x >> 6;
    const int c4  = (threadIdx.x & 63) << 2;
    float s[4] = {0.f, 0.f, 0.f, 0.f}, q[4] = {0.f, 0.f, 0.f, 0.f};
#pragma unroll 8
    for (int i = 0; i < 32; ++i) {
        const int row = blockIdx.x * 128 + i * 4 + sub;
        float4 v = *(const float4*)(X + (size_t)row * 256 + c4);
        s[0] += v.x; q[0] += v.x * v.x;
        s[1] += v.y; q[1] += v.y * v.y;
        s[2] += v.z; q[2] += v.z * v.z;
        s[3] += v.w; q[3] += v.w * v.w;
    }
#pragma unroll
    for (int e = 0; e < 4; ++e) {
        red[sub][c4 + e] = s[e];
        red[sub][256 + c4 + e] = q[e];
    }
    __syncthreads();
    const int t = threadIdx.x;
    const int cp = (blockIdx.x & (NCPY - 1)) * 512;
    float sS = red[0][t] + red[1][t] + red[2][t] + red[3][t];
    float sQ = red[0][256 + t] + red[1][256 + t] + red[2][256 + t] + red[3][256 + t];
    atomicAdd(&st0[cp + t], sS);
    atomicAdd(&st0[cp + 256 + t], sQ);
}

// ---------------- normalize x -> xb(bf16), out = 5*relu(x_bn[:, :64]) ----------------
__global__ __launch_bounds__(256) void norm_x(const float* __restrict__ x,
                                              const float* __restrict__ st0,
                                              const float* __restrict__ g,
                                              const float* __restrict__ b,
                                              unsigned short* __restrict__ xb,
                                              float* __restrict__ out) {
    const int i4 = blockIdx.x * 256 + threadIdx.x;
    const int row = i4 >> 6, c4 = (i4 & 63) << 2;
    float4 xv = *(const float4*)(x + (size_t)row * 256 + c4);
    float sS[4] = {0.f, 0.f, 0.f, 0.f}, sQ[4] = {0.f, 0.f, 0.f, 0.f};
#pragma unroll
    for (int cp = 0; cp < NCPY; ++cp) {
        float4 a = *(const float4*)&st0[cp * 512 + c4];
        float4 q = *(const float4*)&st0[cp * 512 + 256 + c4];
        sS[0] += a.x; sS[1] += a.y; sS[2] += a.z; sS[3] += a.w;
        sQ[0] += q.x; sQ[1] += q.y; sQ[2] += q.z; sQ[3] += q.w;
    }
    float4 gv = *(const float4*)&g[c4];
    float4 bv = *(const float4*)&b[c4];
    const float* xp = (const float*)&xv;
    const float* gp = (const float*)&gv; const float* bp = (const float*)&bv;
    float n[4];
    ushort4 ob;
    unsigned short* obp = (unsigned short*)&ob;
#pragma unroll
    for (int e = 0; e < 4; ++e) {
        float mean = sS[e] * INV_B;
        float var  = sQ[e] * INV_B - mean * mean;
        float sc   = gp[e] * rsqrtf(var + BN_EPS);
        float sh   = bp[e] - mean * sc;
        n[e] = xp[e] * sc + sh;
        obp[e] = f2b(n[e]);
    }
    *(ushort4*)(xb + (size_t)row * 256 + c4) = ob;
    if (c4 < OUTD) {
        float4 ov = make_float4(5.0f * fmaxf(n[0], 0.f), 5.0f * fmaxf(n[1], 0.f),
                                5.0f * fmaxf(n[2], 0.f), 5.0f * fmaxf(n[3], 0.f));
        *(float4*)(out + (size_t)row * OUTD + c4) = ov;
    }
}

// ---------------- shared epilogue (64 rows x 256 cols per block) ----------------
// wave w owns cols [w*64, w*64+64); acc[i][j]: rows i*16, cols j*16.
__device__ __forceinline__ void gemm_epilogue(
    f32x4 (&acc)[4][4], int row0, int wave, int lane, int tid, int bcp,
    float* redS, float* redQ,
    unsigned short* __restrict__ Pout, float* __restrict__ statsOut)
{
    const int fm = lane & 15;
    const int orow = row0 + (lane >> 4) * 4;
    const int ocol = wave * 64 + fm;
#pragma unroll
    for (int i = 0; i < 4; ++i)
#pragma unroll
        for (int j = 0; j < 4; ++j)
#pragma unroll
            for (int r = 0; r < 4; ++r)
                Pout[(size_t)(orow + i * 16 + r) * 256 + (ocol + j * 16)] = f2b(acc[i][j][r]);

#pragma unroll
    for (int j = 0; j < 4; ++j) {
        float s = 0.f, q = 0.f;
#pragma unroll
        for (int i = 0; i < 4; ++i)
#pragma unroll
            for (int r = 0; r < 4; ++r) {
                float v = acc[i][j][r];
                s += v; q += v * v;
            }
        s += __shfl_xor(s, 16, 64); s += __shfl_xor(s, 32, 64);
        q += __shfl_xor(q, 16, 64); q += __shfl_xor(q, 32, 64);
        if (lane < 16) {
            redS[wave * 64 + j * 16 + lane] = s;
            redQ[wave * 64 + j * 16 + lane] = q;
        }
    }
    __syncthreads();
    atomicAdd(&statsOut[bcp + tid], redS[tid]);
    atomicAdd(&statsOut[bcp + 256 + tid], redQ[tid]);
}

// ---------------- stage-1 GEMM: 64x256 tile, A materialized ----------------
__global__ __launch_bounds__(256) void gemm_bf16(
    const unsigned short* __restrict__ A,
    const unsigned short* __restrict__ Wt, int K,
    unsigned short* __restrict__ P,
    float* __restrict__ statsOut)
{
    __shared__ short As[64 * 32];    // 4 KB
    __shared__ short Bs[256 * 32];   // 16 KB
    __shared__ float redS[256], redQ[256];

    const int tid  = threadIdx.x;
    const int wave = tid >> 6;
    const int lane = tid & 63;
    const int row0 = blockIdx.x * 64;
    const int bcp  = (blockIdx.x & (NCPY - 1)) * 512;

    const int sr = lane >> 2;
    const int sc = (lane & 3) * 8;
    const int fm = lane & 15;
    const int fq = (lane >> 4) * 8;

    f32x4 acc[4][4];
#pragma unroll
    for (int i = 0; i < 4; ++i)
#pragma unroll
        for (int j = 0; j < 4; ++j)
            acc[i][j] = (f32x4){0.f, 0.f, 0.f, 0.f};

    for (int k0 = 0; k0 < K; k0 += 32) {
        async16(A + (size_t)(row0 + wave * 16 + sr) * K + k0 + sc,
                (void*)(As + wave * 512 + lane * 8));
#pragma unroll
        for (int t = 0; t < 4; ++t) {
            const int wr = wave * 64 + t * 16 + sr;   // weight output col
            async16(Wt + (size_t)wr * K + k0 + sc,
                    (void*)(Bs + (wave * 4 + t) * 512 + lane * 8));
        }
        __syncthreads();

        bf16x8 af[4], bfr[4];
#pragma unroll
        for (int i = 0; i < 4; ++i)
            af[i] = *(const bf16x8*)(As + (i * 16 + fm) * 32 + fq);
#pragma unroll
        for (int j = 0; j < 4; ++j)
            bfr[j] = *(const bf16x8*)(Bs + (wave * 64 + j * 16 + fm) * 32 + fq);
#pragma unroll
        for (int i = 0; i < 4; ++i)
#pragma unroll
            for (int j = 0; j < 4; ++j)
                acc[i][j] = __builtin_amdgcn_mfma_f32_16x16x32_bf16(af[i], bfr[j], acc[i][j], 0, 0, 0);
        __syncthreads();
    }

    gemm_epilogue(acc, row0, wave, lane, tid, bcp, redS, redQ, P, statsOut);
}

// ---------------- fused BN+GLU(+res) GEMM: 64x256 tile, GLU computed once ----------------
template <bool RES, bool WRITE_H>
__global__ __launch_bounds__(256) void gemm_glu(
    const unsigned short* __restrict__ Pprev,
    const float* __restrict__ pstats,   // 8-copy slot base
    const float* __restrict__ pg,
    const float* __restrict__ pb,
    const unsigned short* __restrict__ res,   // pre-offset, lda 128
    int colOff,
    const unsigned short* __restrict__ Wt, int K,
    unsigned short* __restrict__ Pout,
    float* __restrict__ statsOut,
    unsigned short* __restrict__ hOut)
{
    __shared__ short As[64 * 32];
    __shared__ short Bs[256 * 32];
    __shared__ float redS[256], redQ[256];
    __shared__ float tScA[128], tShA[128], tScG[128], tShG[128];

    const int tid  = threadIdx.x;
    const int wave = tid >> 6;
    const int lane = tid & 63;
    const int row0 = blockIdx.x * 64;
    const int bcp  = (blockIdx.x & (NCPY - 1)) * 512;

    // per-column BN affine tables (sum 8 stat copies)
    if (tid < K) {
        const int ch = colOff + tid;
        const int cg = ch + 128;
        float sA = 0.f, qA = 0.f, sG = 0.f, qG = 0.f;
#pragma unroll
        for (int cp = 0; cp < NCPY; ++cp) {
            const float* p = pstats + cp * 512;
            sA += p[ch]; qA += p[256 + ch];
            sG += p[cg]; qG += p[256 + cg];
        }
        float ma = sA * INV_B, va = qA * INV_B - ma * ma;
        float scA = pg[ch] * rsqrtf(va + BN_EPS);
        tScA[tid] = scA; tShA[tid] = pb[ch] - ma * scA;
        float mg = sG * INV_B, vg = qG * INV_B - mg * mg;
        float scG = pg[cg] * rsqrtf(vg + BN_EPS);
        tScG[tid] = scG; tShG[tid] = pb[cg] - mg * scG;
    }
    __syncthreads();

    const int sr = lane >> 2;
    const int sc = (lane & 3) * 8;
    const int ar = tid >> 2;          // A row 0..63
    const int ac = (tid & 3) * 8;     // A k base
    const int fm = lane & 15;
    const int fq = (lane >> 4) * 8;

    f32x4 acc[4][4];
#pragma unroll
    for (int i = 0; i < 4; ++i)
#pragma unroll
        for (int j = 0; j < 4; ++j)
            acc[i][j] = (f32x4){0.f, 0.f, 0.f, 0.f};

    for (int k0 = 0; k0 < K; k0 += 32) {
        // B staging first (DMAs in flight under the GLU compute)
#pragma unroll
        for (int t = 0; t < 4; ++t) {
            const int wr = wave * 64 + t * 16 + sr;
            async16(Wt + (size_t)wr * K + k0 + sc,
                    (void*)(Bs + (wave * 4 + t) * 512 + lane * 8));
        }

        // A prologue: one bf16x8 per thread, computed ONCE (no col duplication)
        {
            const int kk = k0 + ac;
            const size_t grow = (size_t)(row0 + ar);

            bf16x8 lo = *(const bf16x8*)(Pprev + grow * 256 + colOff + kk);
            bf16x8 hi = *(const bf16x8*)(Pprev + grow * 256 + colOff + kk + 128);
            bf16x8 rv;
            if (RES) rv = *(const bf16x8*)(res + grow * 128 + kk);

            float4 a0 = *(const float4*)&tScA[kk], a1 = *(const float4*)&tScA[kk + 4];
            float4 h0 = *(const float4*)&tShA[kk], h1 = *(const float4*)&tShA[kk + 4];
            float4 g0 = *(const float4*)&tScG[kk], g1 = *(const float4*)&tScG[kk + 4];
            float4 s0 = *(const float4*)&tShG[kk], s1 = *(const float4*)&tShG[kk + 4];
            float scA[8] = {a0.x, a0.y, a0.z, a0.w, a1.x, a1.y, a1.z, a1.w};
            float shA[8] = {h0.x, h0.y, h0.z, h0.w, h1.x, h1.y, h1.z, h1.w};
            float scG[8] = {g0.x, g0.y, g0.z, g0.w, g1.x, g1.y, g1.z, g1.w};
            float shG[8] = {s0.x, s0.y, s0.z, s0.w, s1.x, s1.y, s1.z, s1.w};

            bf16x8 o8;
#pragma unroll
            for (int e = 0; e < 8; ++e) {
                float na = b2f((unsigned short)lo[e]) * scA[e] + shA[e];
                float ng = b2f((unsigned short)hi[e]) * scG[e] + shG[e];
                float v = na * (1.0f / (1.0f + __expf(-ng)));
                if (RES) v = (v + b2f((unsigned short)rv[e])) * SQRT_HALF;
                o8[e] = (short)f2b(v);
            }
            *(bf16x8*)(As + ar * 32 + ac) = o8;
            if (WRITE_H)
                *(bf16x8*)(hOut + grow * 128 + kk) = o8;
        }
        __syncthreads();

        bf16x8 af[4], bfr[4];
#pragma unroll
        for (int i = 0; i < 4; ++i)
            af[i] = *(const bf16x8*)(As + (i * 16 + fm) * 32 + fq);
#pragma unroll
        for (int j = 0; j < 4; ++j)
            bfr[j] = *(const bf16x8*)(Bs + (wave * 64 + j * 16 + fm) * 32 + fq);
#pragma unroll
        for (int i = 0; i < 4; ++i)
#pragma unroll
            for (int j = 0; j < 4; ++j)
                acc[i][j] = __builtin_amdgcn_mfma_f32_16x16x32_bf16(af[i], bfr[j], acc[i][j], 0, 0, 0);
        __syncthreads();
    }

    gemm_epilogue(acc, row0, wave, lane, tid, bcp, redS, redQ, Pout, statsOut);
}

// ---------------- coef BN -> softmax -> mask/compl/entropy ----------------
// MODE 0: first (cmpl==1 implicit). MODE 1: middle. MODE 2: last (entropy only).
template <int MODE>
__global__ __launch_bounds__(256) void coef_mask(const unsigned short* __restrict__ Pc,
                                                 const float* __restrict__ stats,  // 8-copy slot
                                                 const float* __restrict__ gc,
                                                 const float* __restrict__ bc,
                                                 const unsigned short* __restrict__ xb,
                                                 unsigned short* __restrict__ cmpl,
                                                 unsigned short* __restrict__ masked,
                                                 float* __restrict__ ent) {
    const int w    = threadIdx.x >> 6;
    const int lane = threadIdx.x & 63;
    const int row  = blockIdx.x * 4 + w;
    const int c    = lane << 2;
    __shared__ float went[4];

    float sS[4] = {0.f, 0.f, 0.f, 0.f}, sQ[4] = {0.f, 0.f, 0.f, 0.f};
#pragma unroll
    for (int cp = 0; cp < NCPY; ++cp) {
        float4 a = *(const float4*)&stats[cp * 512 + c];
        float4 q = *(const float4*)&stats[cp * 512 + 256 + c];
        sS[0] += a.x; sS[1] += a.y; sS[2] += a.z; sS[3] += a.w;
        sQ[0] += q.x; sQ[1] += q.y; sQ[2] += q.z; sQ[3] += q.w;
    }
    float4 gv = *(const float4*)&gc[c];
    float4 bv = *(const float4*)&bc[c];
    const float* gvv = (const float*)&gv; const float* bvv = (const float*)&bv;

    float scl[4], shf[4];
#pragma unroll
    for (int e = 0; e < 4; ++e) {
        float mean = sS[e] * INV_B, var = sQ[e] * INV_B - mean * mean;
        scl[e] = gvv[e] * rsqrtf(var + BN_EPS);
        shf[e] = bvv[e] - mean * scl[e];
    }

    const size_t idx = (size_t)row * 256 + c;
    ushort4 pu = *(const ushort4*)(Pc + idx);
    const unsigned short* puv = (const unsigned short*)&pu;

    float cl[4] = {1.f, 1.f, 1.f, 1.f};
    if (MODE != 0) {
        ushort4 cu = *(const ushort4*)(cmpl + idx);
        const unsigned short* cuv = (const unsigned short*)&cu;
#pragma unroll
        for (int e = 0; e < 4; ++e) cl[e] = b2f(cuv[e]);
    }

    float l[4];
#pragma unroll
    for (int e = 0; e < 4; ++e) l[e] = (b2f(puv[e]) * scl[e] + shf[e]) * cl[e];

    float mx = waveMaxAll(fmaxf(fmaxf(l[0], l[1]), fmaxf(l[2], l[3])));
    float e0 = __expf(l[0] - mx), e1 = __expf(l[1] - mx),
          e2 = __expf(l[2] - mx), e3 = __expf(l[3] - mx);
    float inv = 1.0f / waveSumAll(e0 + e1 + e2 + e3);

    float m[4] = {e0 * inv, e1 * inv, e2 * inv, e3 * inv};

    float et = -m[0] * __logf(m[0] + SM_EPS) - m[1] * __logf(m[1] + SM_EPS)
             - m[2] * __logf(m[2] + SM_EPS) - m[3] * __logf(m[3] + SM_EPS);
    et = waveSumAll(et);
    if (lane == 0) went[w] = et;
    __syncthreads();
    if (threadIdx.x == 0) {
        float v = went[0] + went[1] + went[2] + went[3];
        atomicAdd(&ent[(blockIdx.x & 255) << 5], v * (INV_B * 0.2f));
    }

    if (MODE != 2) {
        ushort4 xu = *(const ushort4*)(xb + idx);
        const unsigned short* xuv = (const unsigned short*)&xu;
        ushort4 co, mo;
        unsigned short* cop = (unsigned short*)&co;
        unsigned short* mop = (unsigned short*)&mo;
#pragma unroll
        for (int e = 0; e < 4; ++e) {
            cop[e] = f2b(cl[e] * (1.5f - m[e]));
            mop[e] = f2b(m[e] * b2f(xuv[e]));
        }
        *(ushort4*)&cmpl[idx]   = co;
        *(ushort4*)&masked[idx] = mo;
    }
}

__global__ __launch_bounds__(64) void write_ent(const float* __restrict__ ent,
                                                float* __restrict__ dst) {
    const int lane = threadIdx.x;
    float v = 0.f;
#pragma unroll
    for (int i = 0; i < 4; ++i) v += ent[(lane + 64 * i) << 5];
    v = waveSumAll(v);
    if (lane == 0) dst[0] = v;
}

// ---------------- host orchestration ----------------
extern "C" void kernel_launch(void* const* d_in, const int* in_sizes, int n_in,
                              void* d_out, int out_size, void* d_ws, size_t ws_size,
                              hipStream_t stream) {
    const float* x     = (const float*)d_in[0];
    const float* enc_g = (const float*)d_in[1];
    const float* enc_b = (const float*)d_in[2];
    const float* W1 = (const float*)d_in[3];
    const float* g1 = (const float*)d_in[4];
    const float* b1 = (const float*)d_in[5];
    const float* W2 = (const float*)d_in[6];
    const float* g2 = (const float*)d_in[7];
    const float* b2 = (const float*)d_in[8];
    const float* W3 = (const float*)d_in[9];
    const float* g3 = (const float*)d_in[10];
    const float* b3 = (const float*)d_in[11];
    const float* W4 = (const float*)d_in[12];
    const float* g4 = (const float*)d_in[13];
    const float* b4 = (const float*)d_in[14];
    const float* Wc = (const float*)d_in[15];
    const float* gc = (const float*)d_in[16];
    const float* bc = (const float*)d_in[17];
    float* out = (float*)d_out;

    const size_t NBF = (size_t)BSZ * FDIM;   // 8388608
    const size_t NBH = (size_t)BSZ * HDIM;   // 4194304

    unsigned short* xb     = (unsigned short*)d_ws;
    unsigned short* masked = xb + NBF;       // doubles as P ping buffer Pb2
    unsigned short* Pb1    = masked + NBF;
    unsigned short* h1     = Pb1 + NBF;
    unsigned short* h2     = h1 + NBH;
    unsigned short* h3     = h2 + NBH;
    unsigned short* cmpl   = h3 + NBH;
    unsigned short* W1t    = cmpl + NBF;          // 65536
    unsigned short* W2t    = W1t + 65536;         // 32768
    unsigned short* W3t    = W2t + 32768;         // 5*32768
    unsigned short* W4t    = W3t + 163840;        // 5*32768
    unsigned short* Wct    = W4t + 163840;        // 5*16384
    float* stats = (float*)(Wct + 81920);         // 26 slots * 8 copies * 512
    float* ent   = stats + 26 * SLOT;             // 256 slots * 32 (128B spread)

    unsigned short* Pb2 = masked;

    hipMemsetAsync(stats, 0, (26 * SLOT + 256 * 32) * sizeof(float), stream);

    prep_w<<<dim3(17, 8), 256, 0, stream>>>(W1, W2, W3, W4, Wc, W1t, W2t, W3t, W4t, Wct);
    colstats<<<256, 256, 0, stream>>>(x, stats);
    norm_x<<<8192, 256, 0, stream>>>(x, stats, enc_g, enc_b, xb, out);

    for (int ni = 0; ni < 5; ++ni) {
        float* s1 = stats + (size_t)(1 + ni * 5 + 0) * SLOT;
        float* s2 = stats + (size_t)(1 + ni * 5 + 1) * SLOT;
        float* s3 = stats + (size_t)(1 + ni * 5 + 2) * SLOT;
        float* s4 = stats + (size_t)(1 + ni * 5 + 3) * SLOT;
        float* s5 = stats + (size_t)(1 + ni * 5 + 4) * SLOT;

        const unsigned short* in1 = (ni == 0) ? xb : masked;

        gemm_bf16<<<512, 256, 0, stream>>>(in1, W1t, 256, Pb1, s1);
        gemm_glu<false, true><<<512, 256, 0, stream>>>(
            Pb1, s1, g1, b1, nullptr, 0, W2t, 128, Pb2, s2, h1);
        gemm_glu<true, true><<<512, 256, 0, stream>>>(
            Pb2, s2, g2, b2, h1, 0, W3t + (size_t)ni * 32768, 128, Pb1, s3, h2);
        gemm_glu<true, true><<<512, 256, 0, stream>>>(
            Pb1, s3, g3 + ni * 256, b3 + ni * 256, h2, 0,
            W4t + (size_t)ni * 32768, 128, Pb2, s4, h3);
        gemm_glu<true, false><<<512, 256, 0, stream>>>(
            Pb2, s4, g4 + ni * 256, b4 + ni * 256, h3 + 64, 64,
            Wct + (size_t)ni * 16384, 64, Pb1, s5, nullptr);

        if (ni == 0)
            coef_mask<0><<<BSZ / 4, 256, 0, stream>>>(Pb1, s5, gc, bc, xb, cmpl, masked, ent);
        else if (ni < 4)
            coef_mask<1><<<BSZ / 4, 256, 0, stream>>>(Pb1, s5, gc + ni * 256, bc + ni * 256,
                                                      xb, cmpl, masked, ent);
        else
            coef_mask<2><<<BSZ / 4, 256, 0, stream>>>(Pb1, s5, gc + ni * 256, bc + ni * 256,
                                                      xb, cmpl, masked, ent);
    }

    write_ent<<<1, 64, 0, stream>>>(ent, out + (size_t)BSZ * OUTD);
}